// Round 9
// baseline (637.085 us; speedup 1.0000x reference)
//
#include <hip/hip_runtime.h>

// Correctly-rounded float decay constants
#define DEC1 0.36787944117144233f   // exp(-1)    : psp1 decay, layer1 refractory
#define DEC2 0.60653065971263342f   // exp(-1/2)  : psp2 decay, layer2 refractory
#define DEC3 0.77880078307140487f   // exp(-1/4)  : psp3 decay, layer3 refractory

// ---------------------------------------------------------------------------
// Weight re-layout into d_ws:  w1r[c][ky][kx][o] (400 f)  w2r[c][ky][kx][o]
// (576 f)  wupr[o][di][dj][c] pre-flipped for conv_transpose (64 f).
// ---------------------------------------------------------------------------
__global__ void prep_weights(const float* __restrict__ w1,
                             const float* __restrict__ w2,
                             const float* __restrict__ wup,
                             float* __restrict__ wr)
{
    int i = blockIdx.x * 256 + threadIdx.x;
    if (i < 400) {
        int o = i & 7, tap = i >> 3;
        int c = tap / 25, rem = tap % 25, ky = rem / 5, kx = rem % 5;
        wr[i] = w1[((o * 2 + c) * 5 + ky) * 5 + kx];
    }
    if (i < 576) {
        int o = i & 7, tap = i >> 3;
        int c = tap / 9, rem = tap % 9, ky = rem / 3, kx = rem % 3;
        wr[400 + i] = w2[((o * 8 + c) * 3 + ky) * 3 + kx];
    }
    if (i < 64) {
        int c = i & 7, r = i >> 3;
        int dj = r & 1, di = (r >> 1) & 1, o = r >> 2;
        wr[976 + i] = wup[((o * 8 + c) * 2 + (1 - di)) * 2 + (1 - dj)];
    }
}

// spike + following psp, 4 consecutive timesteps (u = float4 over t)
static __device__ __forceinline__ float4 spike_psp4(float4 u, float th, float dref,
                                                    float dq, float& r, float& q)
{
    float4 qv; float v, s;
    v = __fadd_rn(u.x, r); s = (v >= th) ? 1.f : 0.f;
    r = __fsub_rn(__fmul_rn(dref, r), __fmul_rn(th, s));
    q = __fadd_rn(__fmul_rn(dq, q), s); qv.x = q;
    v = __fadd_rn(u.y, r); s = (v >= th) ? 1.f : 0.f;
    r = __fsub_rn(__fmul_rn(dref, r), __fmul_rn(th, s));
    q = __fadd_rn(__fmul_rn(dq, q), s); qv.y = q;
    v = __fadd_rn(u.z, r); s = (v >= th) ? 1.f : 0.f;
    r = __fsub_rn(__fmul_rn(dref, r), __fmul_rn(th, s));
    q = __fadd_rn(__fmul_rn(dq, q), s); qv.z = q;
    v = __fadd_rn(u.w, r); s = (v >= th) ? 1.f : 0.f;
    r = __fsub_rn(__fmul_rn(dref, r), __fmul_rn(th, s));
    q = __fadd_rn(__fmul_rn(dq, q), s); qv.w = q;
    return qv;
}

// final spike (emits hard spikes), 4 timesteps
static __device__ __forceinline__ float4 spike4(float4 u, float th, float dref, float& r)
{
    float4 ov; float v, s;
    v = __fadd_rn(u.x, r); s = (v >= th) ? 1.f : 0.f;
    r = __fsub_rn(__fmul_rn(dref, r), __fmul_rn(th, s)); ov.x = s;
    v = __fadd_rn(u.y, r); s = (v >= th) ? 1.f : 0.f;
    r = __fsub_rn(__fmul_rn(dref, r), __fmul_rn(th, s)); ov.y = s;
    v = __fadd_rn(u.z, r); s = (v >= th) ? 1.f : 0.f;
    r = __fsub_rn(__fmul_rn(dref, r), __fmul_rn(th, s)); ov.z = s;
    v = __fadd_rn(u.w, r); s = (v >= th) ? 1.f : 0.f;
    r = __fsub_rn(__fmul_rn(dref, r), __fmul_rn(th, s)); ov.w = s;
    return ov;
}

// macro params must not be named w/x/y/z (member-capture, R2 failure)
#define FMA4(ACC_, W_, D_) { ACC_.x += (W_)*(D_).x; ACC_.y += (W_)*(D_).y; \
                             ACC_.z += (W_)*(D_).z; ACC_.w += (W_)*(D_).w; }

// psp1 leaky-integrate 4 steps: state in `st`, input X_, write V_ out
#define PSP4(V_, X_, st) { \
    V_.x = __fadd_rn(__fmul_rn(DEC1, st),   X_.x); \
    V_.y = __fadd_rn(__fmul_rn(DEC1, V_.x), X_.y); \
    V_.z = __fadd_rn(__fmul_rn(DEC1, V_.y), X_.z); \
    V_.w = __fadd_rn(__fmul_rn(DEC1, V_.z), X_.w); st = V_.w; }

// ---------------------------------------------------------------------------
// R8 = R7 (conv/rec split, 5 barriers/chunk, padded sP1, prefetch) +
//  (1) ky/c loops unrolled in B-conv & C-conv: 18-25 ds_read_b128 in flight
//      per batch (was 3-5) -> hides ~120cyc LDS latency that R7 exposed
//      (R7 had 320k cyc slack: LDS 67%, VALU 53%, nothing saturated).
//  (2) stage-D pair-chunk store buffering: even chunk's outputs stashed in
//      regs, odd chunk stores 4xfloat4 = 64B-aligned full sectors (tail
//      chunk 24 stored directly). Kills half-sector dirty evictions
//      (WRITE 290 MB vs 210 ideal).
// Math order per accumulator unchanged -> bit-identical output.
// ---------------------------------------------------------------------------
__global__ __launch_bounds__(256, 2)
void snn_fused(const float* __restrict__ spk,
               const float* __restrict__ wr,
               float* __restrict__ out)
{
    const int tid  = threadIdx.x;
    const int b    = blockIdx.x >> 6;
    const int tile = blockIdx.x & 63;
    const int gy0  = (tile >> 3) << 3;
    const int gx0  = (tile & 7) << 3;

    __shared__ float4 sP1[2][2][2][224]; // [parity][ch][thalf][14 rows x 16]
    __shared__ float4 sP2[8][2][100];    // [ch][thalf][10x10 px] (acc then psp2)
    __shared__ float4 sP3[8][2][64];     // [ch][thalf][ 8x8 px]  (acc then psp3)

    // persistent per-thread recurrent state
    float aP0 = 0.f, aP1 = 0.f;
    float rB[4], qB[4];
    float rC[2] = {0.f, 0.f}, qC[2] = {0.f, 0.f};
    float r3[2] = {0.f, 0.f};
#pragma unroll
    for (int i = 0; i < 4; ++i) { rB[i] = 0.f; qB[i] = 0.f; }

    // ---- stage A: psp1 region 14x14, threads 0..195 ----
    const int ary = tid / 14, arx = tid % 14;
    const int aidx = ary * 16 + arx;           // padded row stride 16
    const int aiy = gy0 - 3 + ary, aix = gx0 - 3 + arx;
    const bool avalid = (tid < 196) && (aiy >= 0) && (aiy < 64) && (aix >= 0) && (aix < 64);
    const int aoff0 = avalid ? (((b * 2 + 0) * 64 + aiy) * 64 + aix) * 200 : 0;
    const int aoff1 = avalid ? (((b * 2 + 1) * 64 + aiy) * 64 + aix) * 200 : 0;

    // ---- stage B: thread = (bh = tid>>7, bpx = tid&127 < 100) ----
    const int bh   = __builtin_amdgcn_readfirstlane(tid >> 7);
    const int bpx  = tid & 127;
    int by_, bx_;
    if (bpx < 80) { by_ = bpx >> 3; bx_ = bpx & 7; }
    else          { int t2 = bpx - 80; by_ = t2 >> 1; bx_ = 8 + (t2 & 1); }
    const int by = by_, bx = bx_;
    const int bwr = by * 10 + bx;              // sP2 px index (bijective)
    const int ochB = tid >> 7;                 // B-rec state owner quad

    // ---- C-conv: thread = (ch2 = tid>>7 -> t-half, cop -> och quad, px) ----
    const int ch2  = __builtin_amdgcn_readfirstlane(tid >> 7);
    const int cop  = __builtin_amdgcn_readfirstlane(tid >> 6) & 1;
    const int cpx  = tid & 63;
    const int cy   = cpx >> 3, cx = cpx & 7;
    const int och2 = (tid >> 6) * 2;           // C-rec state owner pair

    // ---- stage D: thread = (od = t>>7, ddi = (t>>6)&1, px) ----
    const int od  = tid >> 7;
    const int ddi = (tid >> 6) & 1;
    const int dpx = tid & 63;
    const int dy  = dpx >> 3, dxx = dpx & 7;
    const int diy = gy0 + dy, dix = gx0 + dxx;

    // bilinear 2x upsample weights (jax.image.resize "linear")
    const float ay  = ddi ? ((diy == 63) ? 1.f : 0.75f) : ((diy == 0) ? 0.f : 0.25f);
    const float byw = ddi ? ((diy == 63) ? 0.f : 0.25f) : ((diy == 0) ? 1.f : 0.75f);
    const float ax0 = (dix == 0)  ? 0.f : 0.25f;   // dj = 0
    const float bx0 = (dix == 0)  ? 1.f : 0.75f;
    const float ax1 = (dix == 63) ? 1.f : 0.75f;   // dj = 1
    const float bx1 = (dix == 63) ? 0.f : 0.25f;
    const int   didx = (dy + 2 + ddi) * 16 + (dxx + 2);
    float* const opbase0 = out + ((((b * 2 + od) * 128 + (2 * diy + ddi)) * 128)
                                  + (2 * dix + 0)) * 200;
    float* const opbase1 = opbase0 + 200;          // dj = 1 site

    // store pairing buffers: previous (even) chunk's outputs [h][dj]
    float4 sprev[2][2];

    // ---- prefetch registers: chunk 0's input ----
    float4 x00 = make_float4(0.f,0.f,0.f,0.f), x01 = x00, x10 = x00, x11 = x00;
    if (avalid) {
        x00 = *(const float4*)(spk + aoff0);
        x01 = *(const float4*)(spk + aoff0 + 4);
        x10 = *(const float4*)(spk + aoff1);
        x11 = *(const float4*)(spk + aoff1 + 4);
    }

#pragma unroll 1
    for (int ck = 0; ck < 25; ++ck) {
        const int t0 = ck * 8;
        const int p  = ck & 1;

        // ================= stage A: psp1 + prefetch next chunk =============
        if (tid < 196) {
            float4 v;
            PSP4(v, x00, aP0); sP1[p][0][0][aidx] = v;
            PSP4(v, x01, aP0); sP1[p][0][1][aidx] = v;
            PSP4(v, x10, aP1); sP1[p][1][0][aidx] = v;
            PSP4(v, x11, aP1); sP1[p][1][1][aidx] = v;
            if (ck < 24 && avalid) {
                x00 = *(const float4*)(spk + aoff0 + t0 + 8);
                x01 = *(const float4*)(spk + aoff0 + t0 + 12);
                x10 = *(const float4*)(spk + aoff1 + t0 + 8);
                x11 = *(const float4*)(spk + aoff1 + t0 + 12);
            }
        }
        __syncthreads();   // b1: sP1[p] ready; prev-chunk C-conv done with sP2

        // ============ stage B-conv: conv1 5x5, all 8 och, one t-half =======
        if (bpx < 100) {
            float4 a[8];
#pragma unroll
            for (int o = 0; o < 8; ++o) a[o] = make_float4(0.f,0.f,0.f,0.f);
#pragma unroll 1
            for (int c = 0; c < 2; ++c) {
#pragma unroll
                for (int ky = 0; ky < 5; ++ky) {
                    const float4* r0 = &sP1[p][c][bh][(by + ky) * 16 + bx];
                    const float*  wrow = wr + (c * 25 + ky * 5) * 8;
#pragma unroll
                    for (int kx = 0; kx < 5; ++kx) {
                        float4 d = r0[kx];
#pragma unroll
                        for (int o = 0; o < 8; ++o) {
                            float wv = wrow[kx * 8 + o];
                            FMA4(a[o], wv, d);
                        }
                    }
                }
            }
#pragma unroll
            for (int o = 0; o < 8; ++o) sP2[o][bh][bwr] = a[o];
        }
        __syncthreads();   // b2: acc ready

        // ============ stage B-rec: spike1 + psp2 in-place on sP2 ===========
        if (bpx < 100) {
#pragma unroll
            for (int j = 0; j < 4; ++j) {
                const int o = ochB * 4 + j;
                float4 u0 = sP2[o][0][bwr];
                float4 u1 = sP2[o][1][bwr];
                float4 q0 = spike_psp4(u0, 30.f, DEC1, DEC2, rB[j], qB[j]);
                sP2[o][0][bwr] = q0;
                float4 q1 = spike_psp4(u1, 30.f, DEC1, DEC2, rB[j], qB[j]);
                sP2[o][1][bwr] = q1;
            }
        }
        __syncthreads();   // b3: psp2 ready

        // ============ stage C-conv: conv2 3x3, och quad, one t-half ========
        {
            float4 a[4];
#pragma unroll
            for (int j = 0; j < 4; ++j) a[j] = make_float4(0.f,0.f,0.f,0.f);
            const float* wC = wr + 400 + cop * 4;
#pragma unroll 2
            for (int c = 0; c < 8; ++c) {
#pragma unroll
                for (int ky = 0; ky < 3; ++ky) {
                    const float4* r0 = &sP2[c][ch2][(cy + ky) * 10 + cx];
                    const float*  wrow = wC + (c * 9 + ky * 3) * 8;
#pragma unroll
                    for (int kx = 0; kx < 3; ++kx) {
                        float4 d = r0[kx];
#pragma unroll
                        for (int j = 0; j < 4; ++j) {
                            float wv = wrow[kx * 8 + j];
                            FMA4(a[j], wv, d);
                        }
                    }
                }
            }
#pragma unroll
            for (int j = 0; j < 4; ++j) sP3[cop * 4 + j][ch2][cpx] = a[j];
        }
        __syncthreads();   // b4: acc ready

        // ============ stage C-rec: spike2 + psp3 in-place on sP3 ===========
        {
#pragma unroll
            for (int j = 0; j < 2; ++j) {
                const int o = och2 + j;
                float4 u0 = sP3[o][0][cpx];
                float4 u1 = sP3[o][1][cpx];
                float4 q0 = spike_psp4(u0, 50.f, DEC2, DEC3, rC[j], qC[j]);
                sP3[o][0][cpx] = q0;
                float4 q1 = spike_psp4(u1, 50.f, DEC2, DEC3, rC[j], qC[j]);
                sP3[o][1][cpx] = q1;
            }
        }
        __syncthreads();   // b5: psp3 ready

        // ============ stage D: convT 2x2 s2 + psp1 bilinear-up + spike3 ====
        {
            float4 scur[2][2];   // [h][dj]
#pragma unroll 1
            for (int h = 0; h < 2; ++h) {
                float4 p3[8];
#pragma unroll
                for (int c = 0; c < 8; ++c) p3[c] = sP3[c][h][dpx];
                float4 P0a = sP1[p][od][h][didx];
                float4 P0b = sP1[p][od][h][didx + 1];
                float4 P0c = sP1[p][od][h][didx + 2];
                float4 P1a = sP1[p][od][h][didx + 16];
                float4 P1b = sP1[p][od][h][didx + 17];
                float4 P1c = sP1[p][od][h][didx + 18];
#pragma unroll
                for (int dj = 0; dj < 2; ++dj) {
                    const float ax  = dj ? ax1 : ax0;
                    const float bxw = dj ? bx1 : bx0;
                    float4 tv = make_float4(0.f, 0.f, 0.f, 0.f);
                    const float* wD = wr + 976 + ((od * 2 + ddi) * 2 + dj) * 8;
#pragma unroll
                    for (int c = 0; c < 8; ++c) {
                        float wv = wD[c];
                        FMA4(tv, wv, p3[c]);
                    }
                    float4 A  = dj ? P0b : P0a;
                    float4 Bv = dj ? P0c : P0b;
                    float4 Cv = dj ? P1b : P1a;
                    float4 Dv = dj ? P1c : P1b;
                    float4 up, u; float ra, rb;
                    ra = __fadd_rn(__fmul_rn(ay, A.x),  __fmul_rn(byw, Cv.x));
                    rb = __fadd_rn(__fmul_rn(ay, Bv.x), __fmul_rn(byw, Dv.x));
                    up.x = __fadd_rn(__fmul_rn(ax, ra), __fmul_rn(bxw, rb));
                    ra = __fadd_rn(__fmul_rn(ay, A.y),  __fmul_rn(byw, Cv.y));
                    rb = __fadd_rn(__fmul_rn(ay, Bv.y), __fmul_rn(byw, Dv.y));
                    up.y = __fadd_rn(__fmul_rn(ax, ra), __fmul_rn(bxw, rb));
                    ra = __fadd_rn(__fmul_rn(ay, A.z),  __fmul_rn(byw, Cv.z));
                    rb = __fadd_rn(__fmul_rn(ay, Bv.z), __fmul_rn(byw, Dv.z));
                    up.z = __fadd_rn(__fmul_rn(ax, ra), __fmul_rn(bxw, rb));
                    ra = __fadd_rn(__fmul_rn(ay, A.w),  __fmul_rn(byw, Cv.w));
                    rb = __fadd_rn(__fmul_rn(ay, Bv.w), __fmul_rn(byw, Dv.w));
                    up.w = __fadd_rn(__fmul_rn(ax, ra), __fmul_rn(bxw, rb));
                    u.x = __fadd_rn(tv.x, up.x);
                    u.y = __fadd_rn(tv.y, up.y);
                    u.z = __fadd_rn(tv.z, up.z);
                    u.w = __fadd_rn(tv.w, up.w);
                    scur[h][dj] = spike4(u, 100.f, DEC3, r3[dj]);
                }
            }
            // ---- sector-aligned stores: pair even+odd chunks (64B/dj site) ----
            if (ck & 1) {
                *(float4*)(opbase0 + t0 - 8) = sprev[0][0];
                *(float4*)(opbase0 + t0 - 4) = sprev[1][0];
                *(float4*)(opbase0 + t0)     = scur[0][0];
                *(float4*)(opbase0 + t0 + 4) = scur[1][0];
                *(float4*)(opbase1 + t0 - 8) = sprev[0][1];
                *(float4*)(opbase1 + t0 - 4) = sprev[1][1];
                *(float4*)(opbase1 + t0)     = scur[0][1];
                *(float4*)(opbase1 + t0 + 4) = scur[1][1];
            } else if (ck == 24) {
                *(float4*)(opbase0 + t0)     = scur[0][0];
                *(float4*)(opbase0 + t0 + 4) = scur[1][0];
                *(float4*)(opbase1 + t0)     = scur[0][1];
                *(float4*)(opbase1 + t0 + 4) = scur[1][1];
            } else {
#pragma unroll
                for (int h = 0; h < 2; ++h)
#pragma unroll
                    for (int dj = 0; dj < 2; ++dj) sprev[h][dj] = scur[h][dj];
            }
        }
        // no end barrier: next A writes sP1[p^1]; sP2 safe until next B-conv
        // (separated by b1'); sP3 safe until next C-conv (separated by b3').
    }
}

extern "C" void kernel_launch(void* const* d_in, const int* in_sizes, int n_in,
                              void* d_out, int out_size, void* d_ws, size_t ws_size,
                              hipStream_t stream)
{
    const float* spk = (const float*)d_in[0];
    const float* w1  = (const float*)d_in[1];
    const float* w2  = (const float*)d_in[2];
    const float* wup = (const float*)d_in[3];
    float* outp = (float*)d_out;
    float* wr   = (float*)d_ws;   // 1040 floats of re-laid-out weights

    prep_weights<<<dim3(3), dim3(256), 0, stream>>>(w1, w2, wup, wr);
    snn_fused<<<dim3(512), dim3(256), 0, stream>>>(spk, wr, outp);
}

// Round 10
// 574.885 us; speedup vs baseline: 1.1082x; 1.1082x over previous
//
#include <hip/hip_runtime.h>

// Correctly-rounded float decay constants
#define DEC1 0.36787944117144233f   // exp(-1)    : psp1 decay, layer1 refractory
#define DEC2 0.60653065971263342f   // exp(-1/2)  : psp2 decay, layer2 refractory
#define DEC3 0.77880078307140487f   // exp(-1/4)  : psp3 decay, layer3 refractory

// ---------------------------------------------------------------------------
// Weight re-layout into d_ws:  w1r[c][ky][kx][o] (400 f)  w2r[c][ky][kx][o]
// (576 f)  wupr[o][di][dj][c] pre-flipped for conv_transpose (64 f).
// ---------------------------------------------------------------------------
__global__ void prep_weights(const float* __restrict__ w1,
                             const float* __restrict__ w2,
                             const float* __restrict__ wup,
                             float* __restrict__ wr)
{
    int i = blockIdx.x * 256 + threadIdx.x;
    if (i < 400) {
        int o = i & 7, tap = i >> 3;
        int c = tap / 25, rem = tap % 25, ky = rem / 5, kx = rem % 5;
        wr[i] = w1[((o * 2 + c) * 5 + ky) * 5 + kx];
    }
    if (i < 576) {
        int o = i & 7, tap = i >> 3;
        int c = tap / 9, rem = tap % 9, ky = rem / 3, kx = rem % 3;
        wr[400 + i] = w2[((o * 8 + c) * 3 + ky) * 3 + kx];
    }
    if (i < 64) {
        int c = i & 7, r = i >> 3;
        int dj = r & 1, di = (r >> 1) & 1, o = r >> 2;
        wr[976 + i] = wup[((o * 8 + c) * 2 + (1 - di)) * 2 + (1 - dj)];
    }
}

// spike + following psp, 4 consecutive timesteps (u = float4 over t)
static __device__ __forceinline__ float4 spike_psp4(float4 u, float th, float dref,
                                                    float dq, float& r, float& q)
{
    float4 qv; float v, s;
    v = __fadd_rn(u.x, r); s = (v >= th) ? 1.f : 0.f;
    r = __fsub_rn(__fmul_rn(dref, r), __fmul_rn(th, s));
    q = __fadd_rn(__fmul_rn(dq, q), s); qv.x = q;
    v = __fadd_rn(u.y, r); s = (v >= th) ? 1.f : 0.f;
    r = __fsub_rn(__fmul_rn(dref, r), __fmul_rn(th, s));
    q = __fadd_rn(__fmul_rn(dq, q), s); qv.y = q;
    v = __fadd_rn(u.z, r); s = (v >= th) ? 1.f : 0.f;
    r = __fsub_rn(__fmul_rn(dref, r), __fmul_rn(th, s));
    q = __fadd_rn(__fmul_rn(dq, q), s); qv.z = q;
    v = __fadd_rn(u.w, r); s = (v >= th) ? 1.f : 0.f;
    r = __fsub_rn(__fmul_rn(dref, r), __fmul_rn(th, s));
    q = __fadd_rn(__fmul_rn(dq, q), s); qv.w = q;
    return qv;
}

// final spike (emits hard spikes), 4 timesteps
static __device__ __forceinline__ float4 spike4(float4 u, float th, float dref, float& r)
{
    float4 ov; float v, s;
    v = __fadd_rn(u.x, r); s = (v >= th) ? 1.f : 0.f;
    r = __fsub_rn(__fmul_rn(dref, r), __fmul_rn(th, s)); ov.x = s;
    v = __fadd_rn(u.y, r); s = (v >= th) ? 1.f : 0.f;
    r = __fsub_rn(__fmul_rn(dref, r), __fmul_rn(th, s)); ov.y = s;
    v = __fadd_rn(u.z, r); s = (v >= th) ? 1.f : 0.f;
    r = __fsub_rn(__fmul_rn(dref, r), __fmul_rn(th, s)); ov.z = s;
    v = __fadd_rn(u.w, r); s = (v >= th) ? 1.f : 0.f;
    r = __fsub_rn(__fmul_rn(dref, r), __fmul_rn(th, s)); ov.w = s;
    return ov;
}

// macro params must not be named w/x/y/z (member-capture, R2 failure)
#define FMA4(ACC_, W_, D_) { ACC_.x += (W_)*(D_).x; ACC_.y += (W_)*(D_).y; \
                             ACC_.z += (W_)*(D_).z; ACC_.w += (W_)*(D_).w; }

// psp1 leaky-integrate 4 steps: state in `st`, input X_, write V_ out
#define PSP4(V_, X_, st) { \
    V_.x = __fadd_rn(__fmul_rn(DEC1, st),   X_.x); \
    V_.y = __fadd_rn(__fmul_rn(DEC1, V_.x), X_.y); \
    V_.z = __fadd_rn(__fmul_rn(DEC1, V_.y), X_.z); \
    V_.w = __fadd_rn(__fmul_rn(DEC1, V_.z), X_.w); st = V_.w; }

// ---------------------------------------------------------------------------
// R9 = strict revert to R7 (best: 402 us). R8's two changes both reverted:
//  - pair-chunk store buffering REGRESSED (+225 MB WRITE, +72 MB FETCH):
//    every-chunk 32B stores keep output lines hot in L2; 2-chunk cadence let
//    128B lines evict half-dirty -> RFO refetch + double write traffic.
//  - ky/c unrolls: VALUBusy dropped 53->46, VGPR 104->116; neutral-at-best.
// R7 structure: conv/rec split (B-conv 50 reads/thread, C-conv 72),
// 5 barriers/chunk, padded sP1 (row stride 16), parity dbuf on sP1,
// register prefetch of next chunk's input. All conv LDS patterns verified
// at the 8-cycle wave64-b128 minimum (all 32 banks covered).
// ---------------------------------------------------------------------------
__global__ __launch_bounds__(256, 2)
void snn_fused(const float* __restrict__ spk,
               const float* __restrict__ wr,
               float* __restrict__ out)
{
    const int tid  = threadIdx.x;
    const int b    = blockIdx.x >> 6;
    const int tile = blockIdx.x & 63;
    const int gy0  = (tile >> 3) << 3;
    const int gx0  = (tile & 7) << 3;

    __shared__ float4 sP1[2][2][2][224]; // [parity][ch][thalf][14 rows x 16]
    __shared__ float4 sP2[8][2][100];    // [ch][thalf][10x10 px] (acc then psp2)
    __shared__ float4 sP3[8][2][64];     // [ch][thalf][ 8x8 px]  (acc then psp3)

    // persistent per-thread recurrent state
    float aP0 = 0.f, aP1 = 0.f;
    float rB[4], qB[4];
    float rC[2] = {0.f, 0.f}, qC[2] = {0.f, 0.f};
    float r3[2] = {0.f, 0.f};
#pragma unroll
    for (int i = 0; i < 4; ++i) { rB[i] = 0.f; qB[i] = 0.f; }

    // ---- stage A: psp1 region 14x14, threads 0..195 ----
    const int ary = tid / 14, arx = tid % 14;
    const int aidx = ary * 16 + arx;           // padded row stride 16
    const int aiy = gy0 - 3 + ary, aix = gx0 - 3 + arx;
    const bool avalid = (tid < 196) && (aiy >= 0) && (aiy < 64) && (aix >= 0) && (aix < 64);
    const int aoff0 = avalid ? (((b * 2 + 0) * 64 + aiy) * 64 + aix) * 200 : 0;
    const int aoff1 = avalid ? (((b * 2 + 1) * 64 + aiy) * 64 + aix) * 200 : 0;

    // ---- stage B: thread = (bh = tid>>7, bpx = tid&127 < 100) ----
    const int bh   = __builtin_amdgcn_readfirstlane(tid >> 7);
    const int bpx  = tid & 127;
    int by_, bx_;
    if (bpx < 80) { by_ = bpx >> 3; bx_ = bpx & 7; }
    else          { int t2 = bpx - 80; by_ = t2 >> 1; bx_ = 8 + (t2 & 1); }
    const int by = by_, bx = bx_;
    const int bwr = by * 10 + bx;              // sP2 px index (bijective)
    const int ochB = tid >> 7;                 // B-rec state owner quad

    // ---- C-conv: thread = (ch2 = tid>>7 -> t-half, cop -> och quad, px) ----
    const int ch2  = __builtin_amdgcn_readfirstlane(tid >> 7);
    const int cop  = __builtin_amdgcn_readfirstlane(tid >> 6) & 1;
    const int cpx  = tid & 63;
    const int cy   = cpx >> 3, cx = cpx & 7;
    const int och2 = (tid >> 6) * 2;           // C-rec state owner pair

    // ---- stage D: thread = (od = t>>7, ddi = (t>>6)&1, px) ----
    const int od  = tid >> 7;
    const int ddi = (tid >> 6) & 1;
    const int dpx = tid & 63;
    const int dy  = dpx >> 3, dxx = dpx & 7;
    const int diy = gy0 + dy, dix = gx0 + dxx;

    // bilinear 2x upsample weights (jax.image.resize "linear")
    const float ay  = ddi ? ((diy == 63) ? 1.f : 0.75f) : ((diy == 0) ? 0.f : 0.25f);
    const float byw = ddi ? ((diy == 63) ? 0.f : 0.25f) : ((diy == 0) ? 1.f : 0.75f);
    const float ax0 = (dix == 0)  ? 0.f : 0.25f;   // dj = 0
    const float bx0 = (dix == 0)  ? 1.f : 0.75f;
    const float ax1 = (dix == 63) ? 1.f : 0.75f;   // dj = 1
    const float bx1 = (dix == 63) ? 0.f : 0.25f;
    const int   didx = (dy + 2 + ddi) * 16 + (dxx + 2);

    // ---- prefetch registers: chunk 0's input ----
    float4 x00 = make_float4(0.f,0.f,0.f,0.f), x01 = x00, x10 = x00, x11 = x00;
    if (avalid) {
        x00 = *(const float4*)(spk + aoff0);
        x01 = *(const float4*)(spk + aoff0 + 4);
        x10 = *(const float4*)(spk + aoff1);
        x11 = *(const float4*)(spk + aoff1 + 4);
    }

#pragma unroll 1
    for (int ck = 0; ck < 25; ++ck) {
        const int t0 = ck * 8;
        const int p  = ck & 1;

        // ================= stage A: psp1 + prefetch next chunk =============
        if (tid < 196) {
            float4 v;
            PSP4(v, x00, aP0); sP1[p][0][0][aidx] = v;
            PSP4(v, x01, aP0); sP1[p][0][1][aidx] = v;
            PSP4(v, x10, aP1); sP1[p][1][0][aidx] = v;
            PSP4(v, x11, aP1); sP1[p][1][1][aidx] = v;
            if (ck < 24 && avalid) {
                x00 = *(const float4*)(spk + aoff0 + t0 + 8);
                x01 = *(const float4*)(spk + aoff0 + t0 + 12);
                x10 = *(const float4*)(spk + aoff1 + t0 + 8);
                x11 = *(const float4*)(spk + aoff1 + t0 + 12);
            }
        }
        __syncthreads();   // b1: sP1[p] ready; prev-chunk C-conv done with sP2

        // ============ stage B-conv: conv1 5x5, all 8 och, one t-half =======
        if (bpx < 100) {
            float4 a[8];
#pragma unroll
            for (int o = 0; o < 8; ++o) a[o] = make_float4(0.f,0.f,0.f,0.f);
#pragma unroll 1
            for (int c = 0; c < 2; ++c) {
#pragma unroll 1
                for (int ky = 0; ky < 5; ++ky) {
                    const float4* r0 = &sP1[p][c][bh][(by + ky) * 16 + bx];
                    const float*  wrow = wr + (c * 25 + ky * 5) * 8;
#pragma unroll
                    for (int kx = 0; kx < 5; ++kx) {
                        float4 d = r0[kx];
#pragma unroll
                        for (int o = 0; o < 8; ++o) {
                            float wv = wrow[kx * 8 + o];
                            FMA4(a[o], wv, d);
                        }
                    }
                }
            }
#pragma unroll
            for (int o = 0; o < 8; ++o) sP2[o][bh][bwr] = a[o];
        }
        __syncthreads();   // b2: acc ready

        // ============ stage B-rec: spike1 + psp2 in-place on sP2 ===========
        if (bpx < 100) {
#pragma unroll
            for (int j = 0; j < 4; ++j) {
                const int o = ochB * 4 + j;
                float4 u0 = sP2[o][0][bwr];
                float4 u1 = sP2[o][1][bwr];
                float4 q0 = spike_psp4(u0, 30.f, DEC1, DEC2, rB[j], qB[j]);
                sP2[o][0][bwr] = q0;
                float4 q1 = spike_psp4(u1, 30.f, DEC1, DEC2, rB[j], qB[j]);
                sP2[o][1][bwr] = q1;
            }
        }
        __syncthreads();   // b3: psp2 ready

        // ============ stage C-conv: conv2 3x3, och quad, one t-half ========
        {
            float4 a[4];
#pragma unroll
            for (int j = 0; j < 4; ++j) a[j] = make_float4(0.f,0.f,0.f,0.f);
            const float* wC = wr + 400 + cop * 4;
#pragma unroll 1
            for (int c = 0; c < 8; ++c) {
#pragma unroll 1
                for (int ky = 0; ky < 3; ++ky) {
                    const float4* r0 = &sP2[c][ch2][(cy + ky) * 10 + cx];
                    const float*  wrow = wC + (c * 9 + ky * 3) * 8;
#pragma unroll
                    for (int kx = 0; kx < 3; ++kx) {
                        float4 d = r0[kx];
#pragma unroll
                        for (int j = 0; j < 4; ++j) {
                            float wv = wrow[kx * 8 + j];
                            FMA4(a[j], wv, d);
                        }
                    }
                }
            }
#pragma unroll
            for (int j = 0; j < 4; ++j) sP3[cop * 4 + j][ch2][cpx] = a[j];
        }
        __syncthreads();   // b4: acc ready

        // ============ stage C-rec: spike2 + psp3 in-place on sP3 ===========
        {
#pragma unroll
            for (int j = 0; j < 2; ++j) {
                const int o = och2 + j;
                float4 u0 = sP3[o][0][cpx];
                float4 u1 = sP3[o][1][cpx];
                float4 q0 = spike_psp4(u0, 50.f, DEC2, DEC3, rC[j], qC[j]);
                sP3[o][0][cpx] = q0;
                float4 q1 = spike_psp4(u1, 50.f, DEC2, DEC3, rC[j], qC[j]);
                sP3[o][1][cpx] = q1;
            }
        }
        __syncthreads();   // b5: psp3 ready

        // ============ stage D: convT 2x2 s2 + psp1 bilinear-up + spike3 ====
        {
#pragma unroll 1
            for (int h = 0; h < 2; ++h) {
                float4 p3[8];
#pragma unroll
                for (int c = 0; c < 8; ++c) p3[c] = sP3[c][h][dpx];
                float4 P0a = sP1[p][od][h][didx];
                float4 P0b = sP1[p][od][h][didx + 1];
                float4 P0c = sP1[p][od][h][didx + 2];
                float4 P1a = sP1[p][od][h][didx + 16];
                float4 P1b = sP1[p][od][h][didx + 17];
                float4 P1c = sP1[p][od][h][didx + 18];
#pragma unroll
                for (int dj = 0; dj < 2; ++dj) {
                    const float ax  = dj ? ax1 : ax0;
                    const float bxw = dj ? bx1 : bx0;
                    float4 tv = make_float4(0.f, 0.f, 0.f, 0.f);
                    const float* wD = wr + 976 + ((od * 2 + ddi) * 2 + dj) * 8;
#pragma unroll
                    for (int c = 0; c < 8; ++c) {
                        float wv = wD[c];
                        FMA4(tv, wv, p3[c]);
                    }
                    float4 A  = dj ? P0b : P0a;
                    float4 Bv = dj ? P0c : P0b;
                    float4 Cv = dj ? P1b : P1a;
                    float4 Dv = dj ? P1c : P1b;
                    float4 up, u; float ra, rb;
                    ra = __fadd_rn(__fmul_rn(ay, A.x),  __fmul_rn(byw, Cv.x));
                    rb = __fadd_rn(__fmul_rn(ay, Bv.x), __fmul_rn(byw, Dv.x));
                    up.x = __fadd_rn(__fmul_rn(ax, ra), __fmul_rn(bxw, rb));
                    ra = __fadd_rn(__fmul_rn(ay, A.y),  __fmul_rn(byw, Cv.y));
                    rb = __fadd_rn(__fmul_rn(ay, Bv.y), __fmul_rn(byw, Dv.y));
                    up.y = __fadd_rn(__fmul_rn(ax, ra), __fmul_rn(bxw, rb));
                    ra = __fadd_rn(__fmul_rn(ay, A.z),  __fmul_rn(byw, Cv.z));
                    rb = __fadd_rn(__fmul_rn(ay, Bv.z), __fmul_rn(byw, Dv.z));
                    up.z = __fadd_rn(__fmul_rn(ax, ra), __fmul_rn(bxw, rb));
                    ra = __fadd_rn(__fmul_rn(ay, A.w),  __fmul_rn(byw, Cv.w));
                    rb = __fadd_rn(__fmul_rn(ay, Bv.w), __fmul_rn(byw, Dv.w));
                    up.w = __fadd_rn(__fmul_rn(ax, ra), __fmul_rn(bxw, rb));
                    u.x = __fadd_rn(tv.x, up.x);
                    u.y = __fadd_rn(tv.y, up.y);
                    u.z = __fadd_rn(tv.z, up.z);
                    u.w = __fadd_rn(tv.w, up.w);
                    float4 ov = spike4(u, 100.f, DEC3, r3[dj]);
                    float* op = out + ((((b * 2 + od) * 128 + (2 * diy + ddi)) * 128)
                                       + (2 * dix + dj)) * 200 + t0 + h * 4;
                    *(float4*)op = ov;
                }
            }
        }
        // no end barrier: next A writes sP1[p^1]; sP2 safe until next B-conv
        // (separated by b1'); sP3 safe until next C-conv (separated by b3').
    }
}

extern "C" void kernel_launch(void* const* d_in, const int* in_sizes, int n_in,
                              void* d_out, int out_size, void* d_ws, size_t ws_size,
                              hipStream_t stream)
{
    const float* spk = (const float*)d_in[0];
    const float* w1  = (const float*)d_in[1];
    const float* w2  = (const float*)d_in[2];
    const float* wup = (const float*)d_in[3];
    float* outp = (float*)d_out;
    float* wr   = (float*)d_ws;   // 1040 floats of re-laid-out weights

    prep_weights<<<dim3(3), dim3(256), 0, stream>>>(w1, w2, wup, wr);
    snn_fused<<<dim3(512), dim3(256), 0, stream>>>(spk, wr, outp);
}

// Round 11
// 573.399 us; speedup vs baseline: 1.1111x; 1.0026x over previous
//
#include <hip/hip_runtime.h>

// Correctly-rounded float decay constants
#define DEC1 0.36787944117144233f   // exp(-1)    : psp1 decay, layer1 refractory
#define DEC2 0.60653065971263342f   // exp(-1/2)  : psp2 decay, layer2 refractory
#define DEC3 0.77880078307140487f   // exp(-1/4)  : psp3 decay, layer3 refractory

// sP1 row stride in float4: 17 (272 B = 4-bank phase shift per row -> 8 rows
// cover 8 distinct phases; stride 16 = 256 B = 0 shift put every row on the
// same banks, serializing A-writes / B-conv / D row-crossing accesses).
#define S1 17

// ---------------------------------------------------------------------------
// Weight re-layout into d_ws:  w1r[c][ky][kx][o] (400 f)  w2r[c][ky][kx][o]
// (576 f)  wupr[o][di][dj][c] pre-flipped for conv_transpose (64 f).
// ---------------------------------------------------------------------------
__global__ void prep_weights(const float* __restrict__ w1,
                             const float* __restrict__ w2,
                             const float* __restrict__ wup,
                             float* __restrict__ wr)
{
    int i = blockIdx.x * 256 + threadIdx.x;
    if (i < 400) {
        int o = i & 7, tap = i >> 3;
        int c = tap / 25, rem = tap % 25, ky = rem / 5, kx = rem % 5;
        wr[i] = w1[((o * 2 + c) * 5 + ky) * 5 + kx];
    }
    if (i < 576) {
        int o = i & 7, tap = i >> 3;
        int c = tap / 9, rem = tap % 9, ky = rem / 3, kx = rem % 3;
        wr[400 + i] = w2[((o * 8 + c) * 3 + ky) * 3 + kx];
    }
    if (i < 64) {
        int c = i & 7, r = i >> 3;
        int dj = r & 1, di = (r >> 1) & 1, o = r >> 2;
        wr[976 + i] = wup[((o * 8 + c) * 2 + (1 - di)) * 2 + (1 - dj)];
    }
}

// spike + following psp, 4 consecutive timesteps (u = float4 over t)
static __device__ __forceinline__ float4 spike_psp4(float4 u, float th, float dref,
                                                    float dq, float& r, float& q)
{
    float4 qv; float v, s;
    v = __fadd_rn(u.x, r); s = (v >= th) ? 1.f : 0.f;
    r = __fsub_rn(__fmul_rn(dref, r), __fmul_rn(th, s));
    q = __fadd_rn(__fmul_rn(dq, q), s); qv.x = q;
    v = __fadd_rn(u.y, r); s = (v >= th) ? 1.f : 0.f;
    r = __fsub_rn(__fmul_rn(dref, r), __fmul_rn(th, s));
    q = __fadd_rn(__fmul_rn(dq, q), s); qv.y = q;
    v = __fadd_rn(u.z, r); s = (v >= th) ? 1.f : 0.f;
    r = __fsub_rn(__fmul_rn(dref, r), __fmul_rn(th, s));
    q = __fadd_rn(__fmul_rn(dq, q), s); qv.z = q;
    v = __fadd_rn(u.w, r); s = (v >= th) ? 1.f : 0.f;
    r = __fsub_rn(__fmul_rn(dref, r), __fmul_rn(th, s));
    q = __fadd_rn(__fmul_rn(dq, q), s); qv.w = q;
    return qv;
}

// final spike (emits hard spikes), 4 timesteps
static __device__ __forceinline__ float4 spike4(float4 u, float th, float dref, float& r)
{
    float4 ov; float v, s;
    v = __fadd_rn(u.x, r); s = (v >= th) ? 1.f : 0.f;
    r = __fsub_rn(__fmul_rn(dref, r), __fmul_rn(th, s)); ov.x = s;
    v = __fadd_rn(u.y, r); s = (v >= th) ? 1.f : 0.f;
    r = __fsub_rn(__fmul_rn(dref, r), __fmul_rn(th, s)); ov.y = s;
    v = __fadd_rn(u.z, r); s = (v >= th) ? 1.f : 0.f;
    r = __fsub_rn(__fmul_rn(dref, r), __fmul_rn(th, s)); ov.z = s;
    v = __fadd_rn(u.w, r); s = (v >= th) ? 1.f : 0.f;
    r = __fsub_rn(__fmul_rn(dref, r), __fmul_rn(th, s)); ov.w = s;
    return ov;
}

// macro params must not be named w/x/y/z (member-capture, R2 failure)
#define FMA4(ACC_, W_, D_) { ACC_.x += (W_)*(D_).x; ACC_.y += (W_)*(D_).y; \
                             ACC_.z += (W_)*(D_).z; ACC_.w += (W_)*(D_).w; }

// psp1 leaky-integrate 4 steps: state in `st`, input X_, write V_ out
#define PSP4(V_, X_, st) { \
    V_.x = __fadd_rn(__fmul_rn(DEC1, st),   X_.x); \
    V_.y = __fadd_rn(__fmul_rn(DEC1, V_.x), X_.y); \
    V_.z = __fadd_rn(__fmul_rn(DEC1, V_.y), X_.z); \
    V_.w = __fadd_rn(__fmul_rn(DEC1, V_.z), X_.w); st = V_.w; }

// ---------------------------------------------------------------------------
// R10 = R9/R7 with ONE isolated change: sP1 row stride 16 -> 17 float4.
// Stride 16 (256 B) is = 0 mod the 128 B bank wrap: all 14 rows start on the
// same bank phase, so A-writes (4.6 rows/wave), B-conv reads (8 rows/wave,
// 50/thread) and D reads (8 rows/wave) serialize same-column lanes.
// Stride 17 (272 B) shifts each row by 4 banks -> 8 concurrent rows hit 8
// distinct phases. LDS 70656 -> 72448 B (still 2 blocks/CU).
// Probes the hypothesis that a large share of the 4.9e7 conflict cycles
// (~20% of kernel) come from sP1 row alignment. Bit-identical output.
// ---------------------------------------------------------------------------
__global__ __launch_bounds__(256, 2)
void snn_fused(const float* __restrict__ spk,
               const float* __restrict__ wr,
               float* __restrict__ out)
{
    const int tid  = threadIdx.x;
    const int b    = blockIdx.x >> 6;
    const int tile = blockIdx.x & 63;
    const int gy0  = (tile >> 3) << 3;
    const int gx0  = (tile & 7) << 3;

    __shared__ float4 sP1[2][2][2][14 * S1]; // [parity][ch][thalf][14 rows x S1]
    __shared__ float4 sP2[8][2][100];    // [ch][thalf][10x10 px] (acc then psp2)
    __shared__ float4 sP3[8][2][64];     // [ch][thalf][ 8x8 px]  (acc then psp3)

    // persistent per-thread recurrent state
    float aP0 = 0.f, aP1 = 0.f;
    float rB[4], qB[4];
    float rC[2] = {0.f, 0.f}, qC[2] = {0.f, 0.f};
    float r3[2] = {0.f, 0.f};
#pragma unroll
    for (int i = 0; i < 4; ++i) { rB[i] = 0.f; qB[i] = 0.f; }

    // ---- stage A: psp1 region 14x14, threads 0..195 ----
    const int ary = tid / 14, arx = tid % 14;
    const int aidx = ary * S1 + arx;           // padded row stride S1
    const int aiy = gy0 - 3 + ary, aix = gx0 - 3 + arx;
    const bool avalid = (tid < 196) && (aiy >= 0) && (aiy < 64) && (aix >= 0) && (aix < 64);
    const int aoff0 = avalid ? (((b * 2 + 0) * 64 + aiy) * 64 + aix) * 200 : 0;
    const int aoff1 = avalid ? (((b * 2 + 1) * 64 + aiy) * 64 + aix) * 200 : 0;

    // ---- stage B: thread = (bh = tid>>7, bpx = tid&127 < 100) ----
    const int bh   = __builtin_amdgcn_readfirstlane(tid >> 7);
    const int bpx  = tid & 127;
    int by_, bx_;
    if (bpx < 80) { by_ = bpx >> 3; bx_ = bpx & 7; }
    else          { int t2 = bpx - 80; by_ = t2 >> 1; bx_ = 8 + (t2 & 1); }
    const int by = by_, bx = bx_;
    const int bwr = by * 10 + bx;              // sP2 px index (bijective)
    const int ochB = tid >> 7;                 // B-rec state owner quad

    // ---- C-conv: thread = (ch2 = tid>>7 -> t-half, cop -> och quad, px) ----
    const int ch2  = __builtin_amdgcn_readfirstlane(tid >> 7);
    const int cop  = __builtin_amdgcn_readfirstlane(tid >> 6) & 1;
    const int cpx  = tid & 63;
    const int cy   = cpx >> 3, cx = cpx & 7;
    const int och2 = (tid >> 6) * 2;           // C-rec state owner pair

    // ---- stage D: thread = (od = t>>7, ddi = (t>>6)&1, px) ----
    const int od  = tid >> 7;
    const int ddi = (tid >> 6) & 1;
    const int dpx = tid & 63;
    const int dy  = dpx >> 3, dxx = dpx & 7;
    const int diy = gy0 + dy, dix = gx0 + dxx;

    // bilinear 2x upsample weights (jax.image.resize "linear")
    const float ay  = ddi ? ((diy == 63) ? 1.f : 0.75f) : ((diy == 0) ? 0.f : 0.25f);
    const float byw = ddi ? ((diy == 63) ? 0.f : 0.25f) : ((diy == 0) ? 1.f : 0.75f);
    const float ax0 = (dix == 0)  ? 0.f : 0.25f;   // dj = 0
    const float bx0 = (dix == 0)  ? 1.f : 0.75f;
    const float ax1 = (dix == 63) ? 1.f : 0.75f;   // dj = 1
    const float bx1 = (dix == 63) ? 0.f : 0.25f;
    const int   didx = (dy + 2 + ddi) * S1 + (dxx + 2);

    // ---- prefetch registers: chunk 0's input ----
    float4 x00 = make_float4(0.f,0.f,0.f,0.f), x01 = x00, x10 = x00, x11 = x00;
    if (avalid) {
        x00 = *(const float4*)(spk + aoff0);
        x01 = *(const float4*)(spk + aoff0 + 4);
        x10 = *(const float4*)(spk + aoff1);
        x11 = *(const float4*)(spk + aoff1 + 4);
    }

#pragma unroll 1
    for (int ck = 0; ck < 25; ++ck) {
        const int t0 = ck * 8;
        const int p  = ck & 1;

        // ================= stage A: psp1 + prefetch next chunk =============
        if (tid < 196) {
            float4 v;
            PSP4(v, x00, aP0); sP1[p][0][0][aidx] = v;
            PSP4(v, x01, aP0); sP1[p][0][1][aidx] = v;
            PSP4(v, x10, aP1); sP1[p][1][0][aidx] = v;
            PSP4(v, x11, aP1); sP1[p][1][1][aidx] = v;
            if (ck < 24 && avalid) {
                x00 = *(const float4*)(spk + aoff0 + t0 + 8);
                x01 = *(const float4*)(spk + aoff0 + t0 + 12);
                x10 = *(const float4*)(spk + aoff1 + t0 + 8);
                x11 = *(const float4*)(spk + aoff1 + t0 + 12);
            }
        }
        __syncthreads();   // b1: sP1[p] ready; prev-chunk C-conv done with sP2

        // ============ stage B-conv: conv1 5x5, all 8 och, one t-half =======
        if (bpx < 100) {
            float4 a[8];
#pragma unroll
            for (int o = 0; o < 8; ++o) a[o] = make_float4(0.f,0.f,0.f,0.f);
#pragma unroll 1
            for (int c = 0; c < 2; ++c) {
#pragma unroll 1
                for (int ky = 0; ky < 5; ++ky) {
                    const float4* r0 = &sP1[p][c][bh][(by + ky) * S1 + bx];
                    const float*  wrow = wr + (c * 25 + ky * 5) * 8;
#pragma unroll
                    for (int kx = 0; kx < 5; ++kx) {
                        float4 d = r0[kx];
#pragma unroll
                        for (int o = 0; o < 8; ++o) {
                            float wv = wrow[kx * 8 + o];
                            FMA4(a[o], wv, d);
                        }
                    }
                }
            }
#pragma unroll
            for (int o = 0; o < 8; ++o) sP2[o][bh][bwr] = a[o];
        }
        __syncthreads();   // b2: acc ready

        // ============ stage B-rec: spike1 + psp2 in-place on sP2 ===========
        if (bpx < 100) {
#pragma unroll
            for (int j = 0; j < 4; ++j) {
                const int o = ochB * 4 + j;
                float4 u0 = sP2[o][0][bwr];
                float4 u1 = sP2[o][1][bwr];
                float4 q0 = spike_psp4(u0, 30.f, DEC1, DEC2, rB[j], qB[j]);
                sP2[o][0][bwr] = q0;
                float4 q1 = spike_psp4(u1, 30.f, DEC1, DEC2, rB[j], qB[j]);
                sP2[o][1][bwr] = q1;
            }
        }
        __syncthreads();   // b3: psp2 ready

        // ============ stage C-conv: conv2 3x3, och quad, one t-half ========
        {
            float4 a[4];
#pragma unroll
            for (int j = 0; j < 4; ++j) a[j] = make_float4(0.f,0.f,0.f,0.f);
            const float* wC = wr + 400 + cop * 4;
#pragma unroll 1
            for (int c = 0; c < 8; ++c) {
#pragma unroll 1
                for (int ky = 0; ky < 3; ++ky) {
                    const float4* r0 = &sP2[c][ch2][(cy + ky) * 10 + cx];
                    const float*  wrow = wC + (c * 9 + ky * 3) * 8;
#pragma unroll
                    for (int kx = 0; kx < 3; ++kx) {
                        float4 d = r0[kx];
#pragma unroll
                        for (int j = 0; j < 4; ++j) {
                            float wv = wrow[kx * 8 + j];
                            FMA4(a[j], wv, d);
                        }
                    }
                }
            }
#pragma unroll
            for (int j = 0; j < 4; ++j) sP3[cop * 4 + j][ch2][cpx] = a[j];
        }
        __syncthreads();   // b4: acc ready

        // ============ stage C-rec: spike2 + psp3 in-place on sP3 ===========
        {
#pragma unroll
            for (int j = 0; j < 2; ++j) {
                const int o = och2 + j;
                float4 u0 = sP3[o][0][cpx];
                float4 u1 = sP3[o][1][cpx];
                float4 q0 = spike_psp4(u0, 50.f, DEC2, DEC3, rC[j], qC[j]);
                sP3[o][0][cpx] = q0;
                float4 q1 = spike_psp4(u1, 50.f, DEC2, DEC3, rC[j], qC[j]);
                sP3[o][1][cpx] = q1;
            }
        }
        __syncthreads();   // b5: psp3 ready

        // ============ stage D: convT 2x2 s2 + psp1 bilinear-up + spike3 ====
        {
#pragma unroll 1
            for (int h = 0; h < 2; ++h) {
                float4 p3[8];
#pragma unroll
                for (int c = 0; c < 8; ++c) p3[c] = sP3[c][h][dpx];
                float4 P0a = sP1[p][od][h][didx];
                float4 P0b = sP1[p][od][h][didx + 1];
                float4 P0c = sP1[p][od][h][didx + 2];
                float4 P1a = sP1[p][od][h][didx + S1];
                float4 P1b = sP1[p][od][h][didx + S1 + 1];
                float4 P1c = sP1[p][od][h][didx + S1 + 2];
#pragma unroll
                for (int dj = 0; dj < 2; ++dj) {
                    const float ax  = dj ? ax1 : ax0;
                    const float bxw = dj ? bx1 : bx0;
                    float4 tv = make_float4(0.f, 0.f, 0.f, 0.f);
                    const float* wD = wr + 976 + ((od * 2 + ddi) * 2 + dj) * 8;
#pragma unroll
                    for (int c = 0; c < 8; ++c) {
                        float wv = wD[c];
                        FMA4(tv, wv, p3[c]);
                    }
                    float4 A  = dj ? P0b : P0a;
                    float4 Bv = dj ? P0c : P0b;
                    float4 Cv = dj ? P1b : P1a;
                    float4 Dv = dj ? P1c : P1b;
                    float4 up, u; float ra, rb;
                    ra = __fadd_rn(__fmul_rn(ay, A.x),  __fmul_rn(byw, Cv.x));
                    rb = __fadd_rn(__fmul_rn(ay, Bv.x), __fmul_rn(byw, Dv.x));
                    up.x = __fadd_rn(__fmul_rn(ax, ra), __fmul_rn(bxw, rb));
                    ra = __fadd_rn(__fmul_rn(ay, A.y),  __fmul_rn(byw, Cv.y));
                    rb = __fadd_rn(__fmul_rn(ay, Bv.y), __fmul_rn(byw, Dv.y));
                    up.y = __fadd_rn(__fmul_rn(ax, ra), __fmul_rn(bxw, rb));
                    ra = __fadd_rn(__fmul_rn(ay, A.z),  __fmul_rn(byw, Cv.z));
                    rb = __fadd_rn(__fmul_rn(ay, Bv.z), __fmul_rn(byw, Dv.z));
                    up.z = __fadd_rn(__fmul_rn(ax, ra), __fmul_rn(bxw, rb));
                    ra = __fadd_rn(__fmul_rn(ay, A.w),  __fmul_rn(byw, Cv.w));
                    rb = __fadd_rn(__fmul_rn(ay, Bv.w), __fmul_rn(byw, Dv.w));
                    up.w = __fadd_rn(__fmul_rn(ax, ra), __fmul_rn(bxw, rb));
                    u.x = __fadd_rn(tv.x, up.x);
                    u.y = __fadd_rn(tv.y, up.y);
                    u.z = __fadd_rn(tv.z, up.z);
                    u.w = __fadd_rn(tv.w, up.w);
                    float4 ov = spike4(u, 100.f, DEC3, r3[dj]);
                    float* op = out + ((((b * 2 + od) * 128 + (2 * diy + ddi)) * 128)
                                       + (2 * dix + dj)) * 200 + t0 + h * 4;
                    *(float4*)op = ov;
                }
            }
        }
        // no end barrier: next A writes sP1[p^1]; sP2 safe until next B-conv
        // (separated by b1'); sP3 safe until next C-conv (separated by b3').
    }
}

extern "C" void kernel_launch(void* const* d_in, const int* in_sizes, int n_in,
                              void* d_out, int out_size, void* d_ws, size_t ws_size,
                              hipStream_t stream)
{
    const float* spk = (const float*)d_in[0];
    const float* w1  = (const float*)d_in[1];
    const float* w2  = (const float*)d_in[2];
    const float* wup = (const float*)d_in[3];
    float* outp = (float*)d_out;
    float* wr   = (float*)d_ws;   // 1040 floats of re-laid-out weights

    prep_weights<<<dim3(3), dim3(256), 0, stream>>>(w1, w2, wup, wr);
    snn_fused<<<dim3(512), dim3(256), 0, stream>>>(spk, wr, outp);
}

// Round 12
// 569.658 us; speedup vs baseline: 1.1184x; 1.0066x over previous
//
#include <hip/hip_runtime.h>

// Correctly-rounded float decay constants
#define DEC1 0.36787944117144233f   // exp(-1)    : psp1 decay, layer1 refractory
#define DEC2 0.60653065971263342f   // exp(-1/2)  : psp2 decay, layer2 refractory
#define DEC3 0.77880078307140487f   // exp(-1/4)  : psp3 decay, layer3 refractory

typedef float v2f __attribute__((ext_vector_type(2)));

// ---------------------------------------------------------------------------
// Weight re-layout into d_ws:  w1r[c][ky][kx][o] (400 f)  w2r[c][ky][kx][o]
// (576 f)  wupr[o][di][dj][c] pre-flipped for conv_transpose (64 f).
// ---------------------------------------------------------------------------
__global__ void prep_weights(const float* __restrict__ w1,
                             const float* __restrict__ w2,
                             const float* __restrict__ wup,
                             float* __restrict__ wr)
{
    int i = blockIdx.x * 256 + threadIdx.x;
    if (i < 400) {
        int o = i & 7, tap = i >> 3;
        int c = tap / 25, rem = tap % 25, ky = rem / 5, kx = rem % 5;
        wr[i] = w1[((o * 2 + c) * 5 + ky) * 5 + kx];
    }
    if (i < 576) {
        int o = i & 7, tap = i >> 3;
        int c = tap / 9, rem = tap % 9, ky = rem / 3, kx = rem % 3;
        wr[400 + i] = w2[((o * 8 + c) * 3 + ky) * 3 + kx];
    }
    if (i < 64) {
        int c = i & 7, r = i >> 3;
        int dj = r & 1, di = (r >> 1) & 1, o = r >> 2;
        wr[976 + i] = wup[((o * 8 + c) * 2 + (1 - di)) * 2 + (1 - dj)];
    }
}

// spike + following psp, 4 consecutive timesteps (u = float4 over t)
static __device__ __forceinline__ float4 spike_psp4(float4 u, float th, float dref,
                                                    float dq, float& r, float& q)
{
    float4 qv; float v, s;
    v = __fadd_rn(u.x, r); s = (v >= th) ? 1.f : 0.f;
    r = __fsub_rn(__fmul_rn(dref, r), __fmul_rn(th, s));
    q = __fadd_rn(__fmul_rn(dq, q), s); qv.x = q;
    v = __fadd_rn(u.y, r); s = (v >= th) ? 1.f : 0.f;
    r = __fsub_rn(__fmul_rn(dref, r), __fmul_rn(th, s));
    q = __fadd_rn(__fmul_rn(dq, q), s); qv.y = q;
    v = __fadd_rn(u.z, r); s = (v >= th) ? 1.f : 0.f;
    r = __fsub_rn(__fmul_rn(dref, r), __fmul_rn(th, s));
    q = __fadd_rn(__fmul_rn(dq, q), s); qv.z = q;
    v = __fadd_rn(u.w, r); s = (v >= th) ? 1.f : 0.f;
    r = __fsub_rn(__fmul_rn(dref, r), __fmul_rn(th, s));
    q = __fadd_rn(__fmul_rn(dq, q), s); qv.w = q;
    return qv;
}

// final spike (emits hard spikes), 4 timesteps
static __device__ __forceinline__ float4 spike4(float4 u, float th, float dref, float& r)
{
    float4 ov; float v, s;
    v = __fadd_rn(u.x, r); s = (v >= th) ? 1.f : 0.f;
    r = __fsub_rn(__fmul_rn(dref, r), __fmul_rn(th, s)); ov.x = s;
    v = __fadd_rn(u.y, r); s = (v >= th) ? 1.f : 0.f;
    r = __fsub_rn(__fmul_rn(dref, r), __fmul_rn(th, s)); ov.y = s;
    v = __fadd_rn(u.z, r); s = (v >= th) ? 1.f : 0.f;
    r = __fsub_rn(__fmul_rn(dref, r), __fmul_rn(th, s)); ov.z = s;
    v = __fadd_rn(u.w, r); s = (v >= th) ? 1.f : 0.f;
    r = __fsub_rn(__fmul_rn(dref, r), __fmul_rn(th, s)); ov.w = s;
    return ov;
}

// packed fma: two independent t-elements per v_pk_fma_f32. Same IEEE fma
// rounding per element, same accumulation order as the scalar FMA4 (which
// was fma-contracted by -O3) -> bit-identical output.
#define PKFMA(ALO_, AHI_, WV_, DLO_, DHI_) { \
    v2f wv2_ = { (WV_), (WV_) }; \
    ALO_ = __builtin_elementwise_fma(wv2_, DLO_, ALO_); \
    AHI_ = __builtin_elementwise_fma(wv2_, DHI_, AHI_); }

// psp1 leaky-integrate 4 steps: state in `st`, input X_, write V_ out
#define PSP4(V_, X_, st) { \
    V_.x = __fadd_rn(__fmul_rn(DEC1, st),   X_.x); \
    V_.y = __fadd_rn(__fmul_rn(DEC1, V_.x), X_.y); \
    V_.z = __fadd_rn(__fmul_rn(DEC1, V_.y), X_.z); \
    V_.w = __fadd_rn(__fmul_rn(DEC1, V_.z), X_.w); st = V_.w; }

// ---------------------------------------------------------------------------
// R11 = R9 (best, 402 us; sP1 stride back to 16 -- R10's 17 was neutral/worse)
// with conv FMAs packed as v2f -> v_pk_fma_f32 (2 FMA/lane/inst):
//   B-conv 1600->800 VALU inst/thread-chunk, C-conv 1152->576, D 128->64.
// Serial recurrences (spike/psp chains) and the bilinear mul/add path keep
// their exact scalar __f*_rn sequences. Bit-identical output expected.
// Probes whether VALU issue rate is the critical path (52% busy at R9).
// ---------------------------------------------------------------------------
__global__ __launch_bounds__(256, 2)
void snn_fused(const float* __restrict__ spk,
               const float* __restrict__ wr,
               float* __restrict__ out)
{
    const int tid  = threadIdx.x;
    const int b    = blockIdx.x >> 6;
    const int tile = blockIdx.x & 63;
    const int gy0  = (tile >> 3) << 3;
    const int gx0  = (tile & 7) << 3;

    __shared__ float4 sP1[2][2][2][224]; // [parity][ch][thalf][14 rows x 16]
    __shared__ float4 sP2[8][2][100];    // [ch][thalf][10x10 px] (acc then psp2)
    __shared__ float4 sP3[8][2][64];     // [ch][thalf][ 8x8 px]  (acc then psp3)

    // persistent per-thread recurrent state
    float aP0 = 0.f, aP1 = 0.f;
    float rB[4], qB[4];
    float rC[2] = {0.f, 0.f}, qC[2] = {0.f, 0.f};
    float r3[2] = {0.f, 0.f};
#pragma unroll
    for (int i = 0; i < 4; ++i) { rB[i] = 0.f; qB[i] = 0.f; }

    // ---- stage A: psp1 region 14x14, threads 0..195 ----
    const int ary = tid / 14, arx = tid % 14;
    const int aidx = ary * 16 + arx;           // padded row stride 16
    const int aiy = gy0 - 3 + ary, aix = gx0 - 3 + arx;
    const bool avalid = (tid < 196) && (aiy >= 0) && (aiy < 64) && (aix >= 0) && (aix < 64);
    const int aoff0 = avalid ? (((b * 2 + 0) * 64 + aiy) * 64 + aix) * 200 : 0;
    const int aoff1 = avalid ? (((b * 2 + 1) * 64 + aiy) * 64 + aix) * 200 : 0;

    // ---- stage B: thread = (bh = tid>>7, bpx = tid&127 < 100) ----
    const int bh   = __builtin_amdgcn_readfirstlane(tid >> 7);
    const int bpx  = tid & 127;
    int by_, bx_;
    if (bpx < 80) { by_ = bpx >> 3; bx_ = bpx & 7; }
    else          { int t2 = bpx - 80; by_ = t2 >> 1; bx_ = 8 + (t2 & 1); }
    const int by = by_, bx = bx_;
    const int bwr = by * 10 + bx;              // sP2 px index (bijective)
    const int ochB = tid >> 7;                 // B-rec state owner quad

    // ---- C-conv: thread = (ch2 = tid>>7 -> t-half, cop -> och quad, px) ----
    const int ch2  = __builtin_amdgcn_readfirstlane(tid >> 7);
    const int cop  = __builtin_amdgcn_readfirstlane(tid >> 6) & 1;
    const int cpx  = tid & 63;
    const int cy   = cpx >> 3, cx = cpx & 7;
    const int och2 = (tid >> 6) * 2;           // C-rec state owner pair

    // ---- stage D: thread = (od = t>>7, ddi = (t>>6)&1, px) ----
    const int od  = tid >> 7;
    const int ddi = (tid >> 6) & 1;
    const int dpx = tid & 63;
    const int dy  = dpx >> 3, dxx = dpx & 7;
    const int diy = gy0 + dy, dix = gx0 + dxx;

    // bilinear 2x upsample weights (jax.image.resize "linear")
    const float ay  = ddi ? ((diy == 63) ? 1.f : 0.75f) : ((diy == 0) ? 0.f : 0.25f);
    const float byw = ddi ? ((diy == 63) ? 0.f : 0.25f) : ((diy == 0) ? 1.f : 0.75f);
    const float ax0 = (dix == 0)  ? 0.f : 0.25f;   // dj = 0
    const float bx0 = (dix == 0)  ? 1.f : 0.75f;
    const float ax1 = (dix == 63) ? 1.f : 0.75f;   // dj = 1
    const float bx1 = (dix == 63) ? 0.f : 0.25f;
    const int   didx = (dy + 2 + ddi) * 16 + (dxx + 2);

    // ---- prefetch registers: chunk 0's input ----
    float4 x00 = make_float4(0.f,0.f,0.f,0.f), x01 = x00, x10 = x00, x11 = x00;
    if (avalid) {
        x00 = *(const float4*)(spk + aoff0);
        x01 = *(const float4*)(spk + aoff0 + 4);
        x10 = *(const float4*)(spk + aoff1);
        x11 = *(const float4*)(spk + aoff1 + 4);
    }

#pragma unroll 1
    for (int ck = 0; ck < 25; ++ck) {
        const int t0 = ck * 8;
        const int p  = ck & 1;

        // ================= stage A: psp1 + prefetch next chunk =============
        if (tid < 196) {
            float4 v;
            PSP4(v, x00, aP0); sP1[p][0][0][aidx] = v;
            PSP4(v, x01, aP0); sP1[p][0][1][aidx] = v;
            PSP4(v, x10, aP1); sP1[p][1][0][aidx] = v;
            PSP4(v, x11, aP1); sP1[p][1][1][aidx] = v;
            if (ck < 24 && avalid) {
                x00 = *(const float4*)(spk + aoff0 + t0 + 8);
                x01 = *(const float4*)(spk + aoff0 + t0 + 12);
                x10 = *(const float4*)(spk + aoff1 + t0 + 8);
                x11 = *(const float4*)(spk + aoff1 + t0 + 12);
            }
        }
        __syncthreads();   // b1: sP1[p] ready; prev-chunk C-conv done with sP2

        // ============ stage B-conv: conv1 5x5, all 8 och, one t-half =======
        if (bpx < 100) {
            v2f alo[8], ahi[8];
#pragma unroll
            for (int o = 0; o < 8; ++o) { alo[o] = (v2f)(0.f); ahi[o] = (v2f)(0.f); }
#pragma unroll 1
            for (int c = 0; c < 2; ++c) {
#pragma unroll 1
                for (int ky = 0; ky < 5; ++ky) {
                    const float4* r0 = &sP1[p][c][bh][(by + ky) * 16 + bx];
                    const float*  wrow = wr + (c * 25 + ky * 5) * 8;
#pragma unroll
                    for (int kx = 0; kx < 5; ++kx) {
                        float4 d = r0[kx];
                        v2f dlo = { d.x, d.y }, dhi = { d.z, d.w };
#pragma unroll
                        for (int o = 0; o < 8; ++o) {
                            float wv = wrow[kx * 8 + o];
                            PKFMA(alo[o], ahi[o], wv, dlo, dhi);
                        }
                    }
                }
            }
#pragma unroll
            for (int o = 0; o < 8; ++o)
                sP2[o][bh][bwr] = make_float4(alo[o].x, alo[o].y, ahi[o].x, ahi[o].y);
        }
        __syncthreads();   // b2: acc ready

        // ============ stage B-rec: spike1 + psp2 in-place on sP2 ===========
        if (bpx < 100) {
#pragma unroll
            for (int j = 0; j < 4; ++j) {
                const int o = ochB * 4 + j;
                float4 u0 = sP2[o][0][bwr];
                float4 u1 = sP2[o][1][bwr];
                float4 q0 = spike_psp4(u0, 30.f, DEC1, DEC2, rB[j], qB[j]);
                sP2[o][0][bwr] = q0;
                float4 q1 = spike_psp4(u1, 30.f, DEC1, DEC2, rB[j], qB[j]);
                sP2[o][1][bwr] = q1;
            }
        }
        __syncthreads();   // b3: psp2 ready

        // ============ stage C-conv: conv2 3x3, och quad, one t-half ========
        {
            v2f alo[4], ahi[4];
#pragma unroll
            for (int j = 0; j < 4; ++j) { alo[j] = (v2f)(0.f); ahi[j] = (v2f)(0.f); }
            const float* wC = wr + 400 + cop * 4;
#pragma unroll 1
            for (int c = 0; c < 8; ++c) {
#pragma unroll 1
                for (int ky = 0; ky < 3; ++ky) {
                    const float4* r0 = &sP2[c][ch2][(cy + ky) * 10 + cx];
                    const float*  wrow = wC + (c * 9 + ky * 3) * 8;
#pragma unroll
                    for (int kx = 0; kx < 3; ++kx) {
                        float4 d = r0[kx];
                        v2f dlo = { d.x, d.y }, dhi = { d.z, d.w };
#pragma unroll
                        for (int j = 0; j < 4; ++j) {
                            float wv = wrow[kx * 8 + j];
                            PKFMA(alo[j], ahi[j], wv, dlo, dhi);
                        }
                    }
                }
            }
#pragma unroll
            for (int j = 0; j < 4; ++j)
                sP3[cop * 4 + j][ch2][cpx] =
                    make_float4(alo[j].x, alo[j].y, ahi[j].x, ahi[j].y);
        }
        __syncthreads();   // b4: acc ready

        // ============ stage C-rec: spike2 + psp3 in-place on sP3 ===========
        {
#pragma unroll
            for (int j = 0; j < 2; ++j) {
                const int o = och2 + j;
                float4 u0 = sP3[o][0][cpx];
                float4 u1 = sP3[o][1][cpx];
                float4 q0 = spike_psp4(u0, 50.f, DEC2, DEC3, rC[j], qC[j]);
                sP3[o][0][cpx] = q0;
                float4 q1 = spike_psp4(u1, 50.f, DEC2, DEC3, rC[j], qC[j]);
                sP3[o][1][cpx] = q1;
            }
        }
        __syncthreads();   // b5: psp3 ready

        // ============ stage D: convT 2x2 s2 + psp1 bilinear-up + spike3 ====
        {
#pragma unroll 1
            for (int h = 0; h < 2; ++h) {
                float4 p3[8];
#pragma unroll
                for (int c = 0; c < 8; ++c) p3[c] = sP3[c][h][dpx];
                float4 P0a = sP1[p][od][h][didx];
                float4 P0b = sP1[p][od][h][didx + 1];
                float4 P0c = sP1[p][od][h][didx + 2];
                float4 P1a = sP1[p][od][h][didx + 16];
                float4 P1b = sP1[p][od][h][didx + 17];
                float4 P1c = sP1[p][od][h][didx + 18];
#pragma unroll
                for (int dj = 0; dj < 2; ++dj) {
                    const float ax  = dj ? ax1 : ax0;
                    const float bxw = dj ? bx1 : bx0;
                    v2f tlo = (v2f)(0.f), thi = (v2f)(0.f);
                    const float* wD = wr + 976 + ((od * 2 + ddi) * 2 + dj) * 8;
#pragma unroll
                    for (int c = 0; c < 8; ++c) {
                        float wv = wD[c];
                        v2f dlo = { p3[c].x, p3[c].y }, dhi = { p3[c].z, p3[c].w };
                        PKFMA(tlo, thi, wv, dlo, dhi);
                    }
                    float4 tv = make_float4(tlo.x, tlo.y, thi.x, thi.y);
                    float4 A  = dj ? P0b : P0a;
                    float4 Bv = dj ? P0c : P0b;
                    float4 Cv = dj ? P1b : P1a;
                    float4 Dv = dj ? P1c : P1b;
                    float4 up, u; float ra, rb;
                    ra = __fadd_rn(__fmul_rn(ay, A.x),  __fmul_rn(byw, Cv.x));
                    rb = __fadd_rn(__fmul_rn(ay, Bv.x), __fmul_rn(byw, Dv.x));
                    up.x = __fadd_rn(__fmul_rn(ax, ra), __fmul_rn(bxw, rb));
                    ra = __fadd_rn(__fmul_rn(ay, A.y),  __fmul_rn(byw, Cv.y));
                    rb = __fadd_rn(__fmul_rn(ay, Bv.y), __fmul_rn(byw, Dv.y));
                    up.y = __fadd_rn(__fmul_rn(ax, ra), __fmul_rn(bxw, rb));
                    ra = __fadd_rn(__fmul_rn(ay, A.z),  __fmul_rn(byw, Cv.z));
                    rb = __fadd_rn(__fmul_rn(ay, Bv.z), __fmul_rn(byw, Dv.z));
                    up.z = __fadd_rn(__fmul_rn(ax, ra), __fmul_rn(bxw, rb));
                    ra = __fadd_rn(__fmul_rn(ay, A.w),  __fmul_rn(byw, Cv.w));
                    rb = __fadd_rn(__fmul_rn(ay, Bv.w), __fmul_rn(byw, Dv.w));
                    up.w = __fadd_rn(__fmul_rn(ax, ra), __fmul_rn(bxw, rb));
                    u.x = __fadd_rn(tv.x, up.x);
                    u.y = __fadd_rn(tv.y, up.y);
                    u.z = __fadd_rn(tv.z, up.z);
                    u.w = __fadd_rn(tv.w, up.w);
                    float4 ov = spike4(u, 100.f, DEC3, r3[dj]);
                    float* op = out + ((((b * 2 + od) * 128 + (2 * diy + ddi)) * 128)
                                       + (2 * dix + dj)) * 200 + t0 + h * 4;
                    *(float4*)op = ov;
                }
            }
        }
        // no end barrier: next A writes sP1[p^1]; sP2 safe until next B-conv
        // (separated by b1'); sP3 safe until next C-conv (separated by b3').
    }
}

extern "C" void kernel_launch(void* const* d_in, const int* in_sizes, int n_in,
                              void* d_out, int out_size, void* d_ws, size_t ws_size,
                              hipStream_t stream)
{
    const float* spk = (const float*)d_in[0];
    const float* w1  = (const float*)d_in[1];
    const float* w2  = (const float*)d_in[2];
    const float* wup = (const float*)d_in[3];
    float* outp = (float*)d_out;
    float* wr   = (float*)d_ws;   // 1040 floats of re-laid-out weights

    prep_weights<<<dim3(3), dim3(256), 0, stream>>>(w1, w2, wup, wr);
    snn_fused<<<dim3(512), dim3(256), 0, stream>>>(spk, wr, outp);
}